// Round 6
// baseline (538.000 us; speedup 1.0000x reference)
//
#include <hip/hip_runtime.h>

// q = rownorm( 1 / (1 + ||x - c||^2) ), ALPHA=1
// x: (262144, 256) f32 ; clusters: (256, 256) f32 ; out: (262144, 256) f32
//
// R6: hybrid B to fix occupancy. R3 (150us) was 1 wave/SIMD because 128KB
// LDS -> 1 block/CU. Here LDS holds only clusters 0..127 (64KB) so TWO
// 256-thread blocks fit per CU (2 waves/SIMD); clusters 128..255 are read
// as register fragments straight from L2 (B-half is L2-resident; loads
// issued at the top of each s-step so the LDS-half MFMAs cover L2 latency).
// Register cap via __launch_bounds__(256,2) = 256 regs; live set ~233.
// (512-thread shapes are poison: compiler caps VGPR at 128 and spills.)

#define NROWS 262144
#define DDIM  256
#define KCL   256
#define TPB   8                       // 64-row tiles per block
#define GRID  (NROWS / 64 / TPB)      // 512 blocks = 2 per CU

using f32x4  = __attribute__((ext_vector_type(4))) float;
using s16x8  = __attribute__((ext_vector_type(8))) short;

__device__ inline unsigned short f2bf(float f) {
    // round-to-nearest-even f32 -> bf16
    unsigned int u = __float_as_uint(f);
    u += 0x7fffu + ((u >> 16) & 1u);
    return (unsigned short)(u >> 16);
}

// One wave per cluster row: convert to bf16, compute ||c||^2.
__global__ void prep_kernel(const float* __restrict__ clusters,
                            unsigned short* __restrict__ cb,
                            float* __restrict__ csq) {
    int k    = blockIdx.x;
    int lane = threadIdx.x;  // 64 threads
    const float* row = clusters + (size_t)k * DDIM;
    float4 a = *reinterpret_cast<const float4*>(row + lane * 4);
    ushort4 b;
    b.x = f2bf(a.x); b.y = f2bf(a.y); b.z = f2bf(a.z); b.w = f2bf(a.w);
    *reinterpret_cast<ushort4*>(cb + (size_t)k * DDIM + lane * 4) = b;
    float ss = a.x*a.x + a.y*a.y + a.z*a.z + a.w*a.w;
    #pragma unroll
    for (int m = 1; m < 64; m <<= 1) ss += __shfl_xor(ss, m);
    if (lane == 0) csq[k] = ss;
}

// 4 waves/block; wave owns 16 rows x 256 cols per tile.
// A-frag: lane holds x[row0 + (l&15)][s*32 + (l>>4)*8 + j], j=0..7
// B-frag: lane holds c[f*16 + (l&15)][s*32 + (l>>4)*8 + j]
//   f = 0..7  -> from LDS (swizzled),  f = 8..15 -> from L2 (global loads)
// C/D   : col = l&15, row = (l>>4)*4 + reg   [verified layout, m89]
__global__ __launch_bounds__(256, 2) void fused_kernel(
    const float* __restrict__ x,
    const unsigned short* __restrict__ cb,
    const float* __restrict__ csq,
    float* __restrict__ out) {

    __shared__ char lds_b[128 * DDIM * 2];   // 64 KB: clusters 0..127, swizzled

    const int tid  = threadIdx.x;
    const int lane = tid & 63;
    const int wave = tid >> 6;               // 0..3
    const int c15  = lane & 15;
    const int kch  = lane >> 4;              // 0..3

    const int tile0 = blockIdx.x * TPB;

    // per-lane base: row ((tile0+t)*64 + wave*16 + c15), col kch*8
    auto xbase = [&](int t) -> const float* {
        return x + (size_t)((tile0 + t) * 64 + wave * 16 + c15) * DDIM + kch * 8;
    };

    f32x4 st[16];   // single prefetch buffer: one tile's 16 rows x 8 floats/lane

    // ---- issue tile 0's x loads (in flight during B staging) ----
    #pragma unroll
    for (int i = 0; i < 16; ++i)
        st[i] = *reinterpret_cast<const f32x4*>(xbase(0) + (i >> 1) * 32 + (i & 1) * 4);

    // ---- stage B lower half into LDS (linear dest, swizzled global source) ----
    #pragma unroll
    for (int it = 0; it < 16; ++it) {
        int slot = it * 4096 + tid * 16;
        int src  = slot ^ (((slot >> 9) & 7) << 4);
        __builtin_amdgcn_global_load_lds(
            (const __attribute__((address_space(1))) unsigned int*)((const char*)cb + src),
            (__attribute__((address_space(3))) unsigned int*)(lds_b + slot),
            16, 0, 0);
    }

    // per-lane global pointer for the upper-half B fragments:
    // cluster (8+f8)*16 + c15, k offset kch*8 ; advance by s*32 each step
    const unsigned short* gb = cb + (size_t)(128 + c15) * DDIM + kch * 8;

    // csq fragment for the epilogue (block-invariant)
    float cs[16];
    #pragma unroll
    for (int f = 0; f < 16; ++f) cs[f] = csq[f * 16 + c15];

    __syncthreads();   // drains vmcnt; B-lower ready

    s16x8 afrag[8];

    // convert st -> afrag + ||x||^2 partials (tree, 4 rotating partials)
    auto convert = [&](float& xsq_out) {
        float p[4] = {0.f, 0.f, 0.f, 0.f};
        #pragma unroll
        for (int s = 0; s < 8; ++s) {
            f32x4 xa = st[2 * s], xb = st[2 * s + 1];
            float t0 = xa[0]*xa[0] + xa[1]*xa[1];
            float t1 = xa[2]*xa[2] + xa[3]*xa[3];
            float t2 = xb[0]*xb[0] + xb[1]*xb[1];
            float t3 = xb[2]*xb[2] + xb[3]*xb[3];
            p[s & 3] += (t0 + t1) + (t2 + t3);
            afrag[s][0] = (short)f2bf(xa[0]); afrag[s][1] = (short)f2bf(xa[1]);
            afrag[s][2] = (short)f2bf(xa[2]); afrag[s][3] = (short)f2bf(xa[3]);
            afrag[s][4] = (short)f2bf(xb[0]); afrag[s][5] = (short)f2bf(xb[1]);
            afrag[s][6] = (short)f2bf(xb[2]); afrag[s][7] = (short)f2bf(xb[3]);
        }
        xsq_out = (p[0] + p[1]) + (p[2] + p[3]);
    };

    auto compute_store = [&](int t, float xsq) {
        f32x4 acc[16];
        #pragma unroll
        for (int f = 0; f < 16; ++f) acc[f] = (f32x4){0.f, 0.f, 0.f, 0.f};

        #pragma unroll
        for (int s = 0; s < 8; ++s) {
            // issue the 8 upper-half B loads for THIS s first (L2 hits);
            // the 8 LDS MFMAs below cover their latency
            s16x8 g[8];
            #pragma unroll
            for (int f8 = 0; f8 < 8; ++f8)
                g[f8] = *reinterpret_cast<const s16x8*>(gb + (size_t)f8 * 16 * DDIM + s * 32);

            #pragma unroll
            for (int f = 0; f < 8; ++f) {
                int ba = (f * 16 + c15) * 512 + s * 64 + kch * 16;
                ba ^= ((c15 & 7) << 4);
                s16x8 bfrag = *reinterpret_cast<const s16x8*>(lds_b + ba);
                acc[f] = __builtin_amdgcn_mfma_f32_16x16x32_bf16(afrag[s], bfrag,
                                                                 acc[f], 0, 0, 0);
            }
            #pragma unroll
            for (int f8 = 0; f8 < 8; ++f8) {
                acc[8 + f8] = __builtin_amdgcn_mfma_f32_16x16x32_bf16(afrag[s], g[f8],
                                                                      acc[8 + f8], 0, 0, 0);
            }
        }

        // combine the 4 kch partials of ||x||^2 (lane l -> row l&15)
        xsq += __shfl_xor(xsq, 16);
        xsq += __shfl_xor(xsq, 32);

        const int row0t = (tile0 + t) * 64 + wave * 16;
        #pragma unroll
        for (int r = 0; r < 4; ++r) {
            float xr = __shfl(xsq, kch * 4 + r);
            float s = 0.f;
            #pragma unroll
            for (int f = 0; f < 16; ++f) {
                float d2 = xr - 2.0f * acc[f][r] + cs[f];
                float qv = 1.0f / (1.0f + d2);   // ALPHA=1 -> exponent == 1
                acc[f][r] = qv;
                s += qv;
            }
            s += __shfl_xor(s, 1);
            s += __shfl_xor(s, 2);
            s += __shfl_xor(s, 4);
            s += __shfl_xor(s, 8);
            float inv = 1.0f / s;
            const size_t orow = (size_t)(row0t + kch * 4 + r) * KCL;
            #pragma unroll
            for (int f = 0; f < 16; ++f) {
                __builtin_nontemporal_store(acc[f][r] * inv, &out[orow + f * 16 + c15]);
            }
        }
    };

    #pragma unroll 1
    for (int t = 0; t < TPB; ++t) {
        float xsq;
        convert(xsq);                       // waits on st loads (long in flight)
        if (t + 1 < TPB) {                  // refill st for tile t+1; loads fly
            #pragma unroll                  // during compute_store
            for (int i = 0; i < 16; ++i)
                st[i] = *reinterpret_cast<const f32x4*>(xbase(t + 1) + (i >> 1) * 32 + (i & 1) * 4);
        }
        compute_store(t, xsq);
    }
}

extern "C" void kernel_launch(void* const* d_in, const int* in_sizes, int n_in,
                              void* d_out, int out_size, void* d_ws, size_t ws_size,
                              hipStream_t stream) {
    const float* x        = (const float*)d_in[0];
    const float* clusters = (const float*)d_in[1];
    float* out = (float*)d_out;

    // ws layout: [0, 128KB) clusters as bf16 ; [128KB, +1KB) c_sq f32
    unsigned short* cb  = (unsigned short*)d_ws;
    float*          csq = (float*)((char*)d_ws + (size_t)KCL * DDIM * sizeof(unsigned short));

    prep_kernel<<<KCL, 64, 0, stream>>>(clusters, cb, csq);
    fused_kernel<<<GRID, 256, 0, stream>>>(x, cb, csq, out);
}

// Round 7
// 490.722 us; speedup vs baseline: 1.0963x; 1.0963x over previous
//
#include <hip/hip_runtime.h>

// q = rownorm( 1 / (1 + ||x - c||^2) ), ALPHA=1
// x: (262144, 256) f32 ; clusters: (256, 256) f32 ; out: (262144, 256) f32
//
// R7: 2 blocks/CU with the arch-register live set actually fitting the cap.
// Allocator model (R2/R4/R5/R6 evidence): unified pool 512/wave-slot; with
// MFMA the budget splits ~half arch / half AGPR, so launch_bounds(256,2)
// gives 128 ARCH regs. R6 spilled because st[16] prefetch (+64) pushed arch
// live to ~150. Here: NO x prefetch buffer — the per-tile load stall is
// hidden by the co-resident second block (the TLP R3 lacked). B hybrid:
// clusters 0..127 in 64KB LDS (swizzled), 128..255 streamed from L2 per
// k-step. Arch live ~100, acc (64) in AGPR half.

#define NROWS 262144
#define DDIM  256
#define KCL   256
#define TPB   8                       // 64-row tiles per block
#define GRID  (NROWS / 64 / TPB)      // 512 blocks = 2 per CU

using f32x4  = __attribute__((ext_vector_type(4))) float;
using s16x8  = __attribute__((ext_vector_type(8))) short;

__device__ inline unsigned short f2bf(float f) {
    // round-to-nearest-even f32 -> bf16
    unsigned int u = __float_as_uint(f);
    u += 0x7fffu + ((u >> 16) & 1u);
    return (unsigned short)(u >> 16);
}

// One wave per cluster row: convert to bf16, compute ||c||^2.
__global__ void prep_kernel(const float* __restrict__ clusters,
                            unsigned short* __restrict__ cb,
                            float* __restrict__ csq) {
    int k    = blockIdx.x;
    int lane = threadIdx.x;  // 64 threads
    const float* row = clusters + (size_t)k * DDIM;
    float4 a = *reinterpret_cast<const float4*>(row + lane * 4);
    ushort4 b;
    b.x = f2bf(a.x); b.y = f2bf(a.y); b.z = f2bf(a.z); b.w = f2bf(a.w);
    *reinterpret_cast<ushort4*>(cb + (size_t)k * DDIM + lane * 4) = b;
    float ss = a.x*a.x + a.y*a.y + a.z*a.z + a.w*a.w;
    #pragma unroll
    for (int m = 1; m < 64; m <<= 1) ss += __shfl_xor(ss, m);
    if (lane == 0) csq[k] = ss;
}

// 4 waves/block; wave owns 16 rows x 256 cols per tile.
// A-frag: lane holds x[row0 + (l&15)][s*32 + (l>>4)*8 + j], j=0..7
// B-frag: lane holds c[f*16 + (l&15)][s*32 + (l>>4)*8 + j]
//   f = 0..7  -> from LDS (swizzled),  f = 8..15 -> from L2 (global loads)
// C/D   : col = l&15, row = (l>>4)*4 + reg   [verified layout, m89]
__global__ __launch_bounds__(256, 2) void fused_kernel(
    const float* __restrict__ x,
    const unsigned short* __restrict__ cb,
    const float* __restrict__ csq,
    float* __restrict__ out) {

    __shared__ char lds_b[128 * DDIM * 2];   // 64 KB: clusters 0..127, swizzled

    const int tid  = threadIdx.x;
    const int lane = tid & 63;
    const int wave = tid >> 6;               // 0..3
    const int c15  = lane & 15;
    const int kch  = lane >> 4;              // 0..3

    const int tile0 = blockIdx.x * TPB;

    // ---- stage B lower half into LDS (linear dest, swizzled global source) ----
    #pragma unroll
    for (int it = 0; it < 16; ++it) {
        int slot = it * 4096 + tid * 16;
        int src  = slot ^ (((slot >> 9) & 7) << 4);
        __builtin_amdgcn_global_load_lds(
            (const __attribute__((address_space(1))) unsigned int*)((const char*)cb + src),
            (__attribute__((address_space(3))) unsigned int*)(lds_b + slot),
            16, 0, 0);
    }

    // per-lane global pointer for the upper-half B fragments:
    // cluster (8+f8)*16 + c15, k offset kch*8 ; advance by s*32 each step
    const unsigned short* gb = cb + (size_t)(128 + c15) * DDIM + kch * 8;

    // csq fragment for the epilogue (block-invariant)
    float cs[16];
    #pragma unroll
    for (int f = 0; f < 16; ++f) cs[f] = csq[f * 16 + c15];

    __syncthreads();   // drains vmcnt; B-lower ready

    #pragma unroll 1
    for (int t = 0; t < TPB; ++t) {
        const float* xrow =
            x + (size_t)((tile0 + t) * 64 + wave * 16 + c15) * DDIM + kch * 8;

        // ---- load + convert this tile's x (regs die after this phase) ----
        s16x8 afrag[8];
        float xsq;
        {
            f32x4 xv[16];
            #pragma unroll
            for (int i = 0; i < 16; ++i)
                xv[i] = *reinterpret_cast<const f32x4*>(xrow + (i >> 1) * 32 + (i & 1) * 4);
            float p[4] = {0.f, 0.f, 0.f, 0.f};
            #pragma unroll
            for (int s = 0; s < 8; ++s) {
                f32x4 xa = xv[2 * s], xb = xv[2 * s + 1];
                float t0 = xa[0]*xa[0] + xa[1]*xa[1];
                float t1 = xa[2]*xa[2] + xa[3]*xa[3];
                float t2 = xb[0]*xb[0] + xb[1]*xb[1];
                float t3 = xb[2]*xb[2] + xb[3]*xb[3];
                p[s & 3] += (t0 + t1) + (t2 + t3);
                afrag[s][0] = (short)f2bf(xa[0]); afrag[s][1] = (short)f2bf(xa[1]);
                afrag[s][2] = (short)f2bf(xa[2]); afrag[s][3] = (short)f2bf(xa[3]);
                afrag[s][4] = (short)f2bf(xb[0]); afrag[s][5] = (short)f2bf(xb[1]);
                afrag[s][6] = (short)f2bf(xb[2]); afrag[s][7] = (short)f2bf(xb[3]);
            }
            xsq = (p[0] + p[1]) + (p[2] + p[3]);
        }

        // ---- 128 MFMAs: 8 frags from LDS + 8 frags from L2 per k-step ----
        f32x4 acc[16];
        #pragma unroll
        for (int f = 0; f < 16; ++f) acc[f] = (f32x4){0.f, 0.f, 0.f, 0.f};

        #pragma unroll
        for (int s = 0; s < 8; ++s) {
            // issue the 8 upper-half B loads first (L2 hits); the 8 LDS
            // MFMAs below cover their latency
            s16x8 g[8];
            #pragma unroll
            for (int f8 = 0; f8 < 8; ++f8)
                g[f8] = *reinterpret_cast<const s16x8*>(gb + (size_t)f8 * 16 * DDIM + s * 32);

            #pragma unroll
            for (int f = 0; f < 8; ++f) {
                int ba = (f * 16 + c15) * 512 + s * 64 + kch * 16;
                ba ^= ((c15 & 7) << 4);
                s16x8 bfrag = *reinterpret_cast<const s16x8*>(lds_b + ba);
                acc[f] = __builtin_amdgcn_mfma_f32_16x16x32_bf16(afrag[s], bfrag,
                                                                 acc[f], 0, 0, 0);
            }
            #pragma unroll
            for (int f8 = 0; f8 < 8; ++f8) {
                acc[8 + f8] = __builtin_amdgcn_mfma_f32_16x16x32_bf16(afrag[s], g[f8],
                                                                      acc[8 + f8], 0, 0, 0);
            }
        }

        // ---- epilogue: student-t + row-normalize + NT store ----
        // combine the 4 kch partials of ||x||^2 (lane l -> row l&15)
        xsq += __shfl_xor(xsq, 16);
        xsq += __shfl_xor(xsq, 32);

        const int row0t = (tile0 + t) * 64 + wave * 16;
        #pragma unroll
        for (int r = 0; r < 4; ++r) {
            float xr = __shfl(xsq, kch * 4 + r);
            float s = 0.f;
            #pragma unroll
            for (int f = 0; f < 16; ++f) {
                float d2 = xr - 2.0f * acc[f][r] + cs[f];
                float qv = 1.0f / (1.0f + d2);   // ALPHA=1 -> exponent == 1
                acc[f][r] = qv;
                s += qv;
            }
            s += __shfl_xor(s, 1);
            s += __shfl_xor(s, 2);
            s += __shfl_xor(s, 4);
            s += __shfl_xor(s, 8);
            float inv = 1.0f / s;
            const size_t orow = (size_t)(row0t + kch * 4 + r) * KCL;
            #pragma unroll
            for (int f = 0; f < 16; ++f) {
                __builtin_nontemporal_store(acc[f][r] * inv, &out[orow + f * 16 + c15]);
            }
        }
    }
}

extern "C" void kernel_launch(void* const* d_in, const int* in_sizes, int n_in,
                              void* d_out, int out_size, void* d_ws, size_t ws_size,
                              hipStream_t stream) {
    const float* x        = (const float*)d_in[0];
    const float* clusters = (const float*)d_in[1];
    float* out = (float*)d_out;

    // ws layout: [0, 128KB) clusters as bf16 ; [128KB, +1KB) c_sq f32
    unsigned short* cb  = (unsigned short*)d_ws;
    float*          csq = (float*)((char*)d_ws + (size_t)KCL * DDIM * sizeof(unsigned short));

    prep_kernel<<<KCL, 64, 0, stream>>>(clusters, cb, csq);
    fused_kernel<<<GRID, 256, 0, stream>>>(x, cb, csq, out);
}

// Round 8
// 135.517 us; speedup vs baseline: 3.9700x; 3.6211x over previous
//
#include <hip/hip_runtime.h>

// q = rownorm( 1 / (1 + ||x - c||^2) ), ALPHA=1
// x: (262144, 256) f32 ; clusters: (256, 256) f32 ; out: (262144, 256) f32
//
// R8: column-split wave pairs. 512 thr / 8 waves, full B (128KB) in LDS once,
// 1 block/CU -> 2 waves/SIMD (TLP). Each wave owns 16 rows x 128 COLS
// (ch = wave&1), so acc = 32 regs, cs = 8, B reads halved; arch live ~90-110
// fits the 128-arch cap that (512,2)/(256,2) impose (R4-R7 all spilled at
// ~150 arch live). Row sums completed by a cross-pair exchange through a
// tiny double-buffered LDS array + one barrier per tile.

#define NROWS 262144
#define DDIM  256
#define KCL   256
#define TPB   16                      // 64-row tiles per block
#define GRID  (NROWS / 64 / TPB)      // 256 blocks = 1 per CU

using f32x4  = __attribute__((ext_vector_type(4))) float;
using s16x8  = __attribute__((ext_vector_type(8))) short;

__device__ inline unsigned short f2bf(float f) {
    // round-to-nearest-even f32 -> bf16
    unsigned int u = __float_as_uint(f);
    u += 0x7fffu + ((u >> 16) & 1u);
    return (unsigned short)(u >> 16);
}

// One wave per cluster row: convert to bf16, compute ||c||^2.
__global__ void prep_kernel(const float* __restrict__ clusters,
                            unsigned short* __restrict__ cb,
                            float* __restrict__ csq) {
    int k    = blockIdx.x;
    int lane = threadIdx.x;  // 64 threads
    const float* row = clusters + (size_t)k * DDIM;
    float4 a = *reinterpret_cast<const float4*>(row + lane * 4);
    ushort4 b;
    b.x = f2bf(a.x); b.y = f2bf(a.y); b.z = f2bf(a.z); b.w = f2bf(a.w);
    *reinterpret_cast<ushort4*>(cb + (size_t)k * DDIM + lane * 4) = b;
    float ss = a.x*a.x + a.y*a.y + a.z*a.z + a.w*a.w;
    #pragma unroll
    for (int m = 1; m < 64; m <<= 1) ss += __shfl_xor(ss, m);
    if (lane == 0) csq[k] = ss;
}

// 8 waves/block: wave w -> rg = w>>1 (row group), ch = w&1 (col half).
// Wave computes rows [trow+rg*16, +16) x cols [ch*128, +128).
// A-frag: lane holds x[row + (l&15)][s*32 + (l>>4)*8 + j], j=0..7
// B-frag: lane holds c[ch*128 + f*16 + (l&15)][s*32 + (l>>4)*8 + j], f=0..7
// C/D   : col = l&15, row = (l>>4)*4 + reg   [verified layout, m89]
__global__ __launch_bounds__(512, 2) void fused_kernel(
    const float* __restrict__ x,
    const unsigned short* __restrict__ cb,
    const float* __restrict__ csq,
    float* __restrict__ out) {

    __shared__ char  lds_b[KCL * DDIM * 2];   // 128 KB: full B, swizzled
    __shared__ float ls_sum[2][2][4][16];     // [t&1][ch][rg][row] partial sums

    const int tid  = threadIdx.x;
    const int lane = tid & 63;
    const int wave = tid >> 6;               // 0..7
    const int rg   = wave >> 1;              // 0..3
    const int ch   = wave & 1;               // 0..1
    const int c15  = lane & 15;
    const int kch  = lane >> 4;              // 0..3

    const int tile0 = blockIdx.x * TPB;

    // ---- stage full B into LDS (linear dest, swizzled global source) ----
    #pragma unroll
    for (int it = 0; it < 16; ++it) {
        int slot = it * 8192 + tid * 16;
        int src  = slot ^ (((slot >> 9) & 7) << 4);
        __builtin_amdgcn_global_load_lds(
            (const __attribute__((address_space(1))) unsigned int*)((const char*)cb + src),
            (__attribute__((address_space(3))) unsigned int*)(lds_b + slot),
            16, 0, 0);
    }

    // csq fragment for this wave's col half (8 regs)
    float cs[8];
    #pragma unroll
    for (int f = 0; f < 8; ++f) cs[f] = csq[ch * 128 + f * 16 + c15];

    __syncthreads();   // drains vmcnt; B ready

    #pragma unroll 1
    for (int t = 0; t < TPB; ++t) {
        const int trow = (tile0 + t) * 64;
        const float* xrow =
            x + (size_t)(trow + rg * 16 + c15) * DDIM + kch * 8;

        // ---- load + convert this tile's x in two 8-load batches ----
        s16x8 afrag[8];
        float xsq;
        {
            float p[4] = {0.f, 0.f, 0.f, 0.f};
            #pragma unroll
            for (int h = 0; h < 2; ++h) {
                f32x4 xv[8];
                #pragma unroll
                for (int i = 0; i < 8; ++i) {
                    int ii = h * 8 + i;
                    xv[i] = *reinterpret_cast<const f32x4*>(xrow + (ii >> 1) * 32 + (ii & 1) * 4);
                }
                #pragma unroll
                for (int s4 = 0; s4 < 4; ++s4) {
                    int s = h * 4 + s4;
                    f32x4 xa = xv[2 * s4], xb = xv[2 * s4 + 1];
                    float t0 = xa[0]*xa[0] + xa[1]*xa[1];
                    float t1 = xa[2]*xa[2] + xa[3]*xa[3];
                    float t2 = xb[0]*xb[0] + xb[1]*xb[1];
                    float t3 = xb[2]*xb[2] + xb[3]*xb[3];
                    p[s & 3] += (t0 + t1) + (t2 + t3);
                    afrag[s][0] = (short)f2bf(xa[0]); afrag[s][1] = (short)f2bf(xa[1]);
                    afrag[s][2] = (short)f2bf(xa[2]); afrag[s][3] = (short)f2bf(xa[3]);
                    afrag[s][4] = (short)f2bf(xb[0]); afrag[s][5] = (short)f2bf(xb[1]);
                    afrag[s][6] = (short)f2bf(xb[2]); afrag[s][7] = (short)f2bf(xb[3]);
                }
            }
            xsq = (p[0] + p[1]) + (p[2] + p[3]);
        }

        // ---- 64 MFMAs: this wave's 8 B-frags (col half) x 8 k-steps ----
        f32x4 acc[8];
        #pragma unroll
        for (int f = 0; f < 8; ++f) acc[f] = (f32x4){0.f, 0.f, 0.f, 0.f};

        #pragma unroll
        for (int s = 0; s < 8; ++s) {
            #pragma unroll
            for (int f = 0; f < 8; ++f) {
                int ba = ((ch * 128 + f * 16 + c15) * 512) + s * 64 + kch * 16;
                ba ^= ((c15 & 7) << 4);
                s16x8 bfrag = *reinterpret_cast<const s16x8*>(lds_b + ba);
                acc[f] = __builtin_amdgcn_mfma_f32_16x16x32_bf16(afrag[s], bfrag,
                                                                 acc[f], 0, 0, 0);
            }
        }

        // ---- partial epilogue: student-t + 128-col partial row sums ----
        xsq += __shfl_xor(xsq, 16);
        xsq += __shfl_xor(xsq, 32);
        // lane l now holds xsq of row trow + rg*16 + (l&15)

        float psum[4];
        #pragma unroll
        for (int r = 0; r < 4; ++r) {
            float xr = __shfl(xsq, kch * 4 + r);
            float s = 0.f;
            #pragma unroll
            for (int f = 0; f < 8; ++f) {
                float d2 = xr - 2.0f * acc[f][r] + cs[f];
                float qv = 1.0f / (1.0f + d2);   // ALPHA=1 -> exponent == 1
                acc[f][r] = qv;
                s += qv;
            }
            s += __shfl_xor(s, 1);
            s += __shfl_xor(s, 2);
            s += __shfl_xor(s, 4);
            s += __shfl_xor(s, 8);
            psum[r] = s;   // sum over this wave's 128 cols, row kch*4+r
        }

        // ---- cross-pair exchange: write own partials, barrier, read other ----
        if (c15 == 0) {
            #pragma unroll
            for (int r = 0; r < 4; ++r)
                ls_sum[t & 1][ch][rg][kch * 4 + r] = psum[r];
        }
        __syncthreads();

        const int row0t = trow + rg * 16;
        #pragma unroll
        for (int r = 0; r < 4; ++r) {
            float other = ls_sum[t & 1][ch ^ 1][rg][kch * 4 + r];
            float inv = 1.0f / (psum[r] + other);
            const size_t orow = (size_t)(row0t + kch * 4 + r) * KCL;
            #pragma unroll
            for (int f = 0; f < 8; ++f) {
                __builtin_nontemporal_store(acc[f][r] * inv,
                                            &out[orow + ch * 128 + f * 16 + c15]);
            }
        }
    }
}

extern "C" void kernel_launch(void* const* d_in, const int* in_sizes, int n_in,
                              void* d_out, int out_size, void* d_ws, size_t ws_size,
                              hipStream_t stream) {
    const float* x        = (const float*)d_in[0];
    const float* clusters = (const float*)d_in[1];
    float* out = (float*)d_out;

    // ws layout: [0, 128KB) clusters as bf16 ; [128KB, +1KB) c_sq f32
    unsigned short* cb  = (unsigned short*)d_ws;
    float*          csq = (float*)((char*)d_ws + (size_t)KCL * DDIM * sizeof(unsigned short));

    prep_kernel<<<KCL, 64, 0, stream>>>(clusters, cb, csq);
    fused_kernel<<<GRID, 512, 0, stream>>>(x, cb, csq, out);
}